// Round 1
// baseline (8870.995 us; speedup 1.0000x reference)
//
#include <hip/hip_runtime.h>
#include <math.h>

#define T 128
#define KN 14      // graph nodes
#define HM 64
#define HF 32
#define F 1024
#define TK (T*KN)   // 1792
#define KF (KN*F)   // 14336

// ---------------- prep: An (gcn_norm) + reset flags ----------------
__global__ void prep_kernel(const float* __restrict__ A, const int* __restrict__ vid,
                            float* __restrict__ An, int* __restrict__ rf, int* __restrict__ rb) {
  __shared__ float dinv[KN];
  int tid = threadIdx.x;
  if (tid < KN) {
    float s = 0.f;
    for (int j = 0; j < KN; ++j) {
      float ab = (A[tid*KN + j] != 0.f) ? 1.f : 0.f;
      if (j == tid) ab += 1.f;
      s += ab;
    }
    dinv[tid] = 1.0f / sqrtf(s);
  }
  __syncthreads();
  if (tid < KN*KN) {
    int i = tid / KN, j = tid % KN;
    float ab = (A[i*KN + j] != 0.f) ? 1.f : 0.f;
    if (i == j) ab += 1.f;
    An[tid] = dinv[i] * ab * dinv[j];
  }
  if (tid < T) {
    rf[tid] = (tid == 0) || (vid[tid] != vid[tid-1]);
    rb[tid] = (tid == 0) || (vid[T-1-tid] != vid[T-tid]);
  }
}

// ---------------- downsample: x (T,K,64,64) -> feat (T,K,1024) ----------------
__global__ void downsample_kernel(const float* __restrict__ x, float* __restrict__ feat) {
  __shared__ float xt[HM*HM];
  int b = blockIdx.x; // t*KN + k
  const float* xp = x + (size_t)b*HM*HM;
  int tid = threadIdx.x;
  #pragma unroll
  for (int i = 0; i < 4; ++i)
    ((float4*)xt)[tid + i*256] = ((const float4*)xp)[tid + i*256];
  __syncthreads();
  const float r = 63.0f/31.0f;
  float* fp = feat + (size_t)b*F;
  #pragma unroll
  for (int i = 0; i < 4; ++i) {
    int idx = tid + i*256;
    int o = idx >> 5, p = idx & 31;
    float co = (float)o * r; int io = (int)floorf(co); int io1 = min(io+1, HM-1); float wo = co - (float)io;
    float cp = (float)p * r; int jp = (int)floorf(cp); int jp1 = min(jp+1, HM-1); float wp = cp - (float)jp;
    float v = (1.f-wo)*((1.f-wp)*xt[io*HM+jp]  + wp*xt[io*HM+jp1])
            +      wo *((1.f-wp)*xt[io1*HM+jp] + wp*xt[io1*HM+jp1]);
    fp[idx] = v;
  }
}

// ---------------- fp32 tiled GEMM: C(M,N) = A(M,K)@B(K,N) (+bias) ----------------
#define BM 128
#define BN 64
#define BK 8
__global__ __launch_bounds__(256) void gemm_kernel(const float* __restrict__ A, int lda,
    const float* __restrict__ B, int ldb, const float* __restrict__ bias,
    float* __restrict__ C, int ldc, int Kd) {
  __shared__ float As[BK][BM];
  __shared__ float Bs[BK][BN];
  int tid = threadIdx.x;
  int tx = tid & 15, ty = tid >> 4;
  int mBase = blockIdx.y*BM, nBase = blockIdx.x*BN;
  float acc[8][4];
  #pragma unroll
  for (int i = 0; i < 8; ++i)
    #pragma unroll
    for (int j = 0; j < 4; ++j) acc[i][j] = 0.f;
  int mL = tid >> 1, kpL = (tid & 1) * 4;
  int kbL = tid >> 5, npL = (tid & 31) * 2;
  for (int k0 = 0; k0 < Kd; k0 += BK) {
    float4 a4 = *(const float4*)(A + (size_t)(mBase + mL)*lda + k0 + kpL);
    As[kpL+0][mL] = a4.x; As[kpL+1][mL] = a4.y; As[kpL+2][mL] = a4.z; As[kpL+3][mL] = a4.w;
    float2 b2 = *(const float2*)(B + (size_t)(k0 + kbL)*ldb + nBase + npL);
    *(float2*)&Bs[kbL][npL] = b2;
    __syncthreads();
    #pragma unroll
    for (int kk = 0; kk < BK; ++kk) {
      float a[8], bb[4];
      *(float4*)&a[0] = *(const float4*)&As[kk][ty*8];
      *(float4*)&a[4] = *(const float4*)&As[kk][ty*8+4];
      *(float4*)&bb[0] = *(const float4*)&Bs[kk][tx*4];
      #pragma unroll
      for (int i = 0; i < 8; ++i)
        #pragma unroll
        for (int j = 0; j < 4; ++j) acc[i][j] = fmaf(a[i], bb[j], acc[i][j]);
    }
    __syncthreads();
  }
  #pragma unroll
  for (int i = 0; i < 8; ++i) {
    float4 v;
    v.x = acc[i][0]; v.y = acc[i][1]; v.z = acc[i][2]; v.w = acc[i][3];
    if (bias) {
      v.x += bias[nBase + tx*4 + 0];
      v.y += bias[nBase + tx*4 + 1];
      v.z += bias[nBase + tx*4 + 2];
      v.w += bias[nBase + tx*4 + 3];
    }
    *(float4*)(C + (size_t)(mBase + ty*8 + i)*ldc + nBase + tx*4) = v;
  }
}

// ---------------- An-mix over node dim (+bias, opt relu) ----------------
__global__ void anmix_kernel(const float* __restrict__ in, const float* __restrict__ An,
                             const float* __restrict__ bias, float* __restrict__ out, int relu) {
  __shared__ float an[KN*KN];
  int t = blockIdx.x, tid = threadIdx.x;
  if (tid < KN*KN) an[tid] = An[tid];
  __syncthreads();
  const float* ip = in + (size_t)t*KF;
  float* op = out + (size_t)t*KF;
  #pragma unroll
  for (int i = 0; i < 4; ++i) {
    int f = tid + i*256;
    float v[KN];
    #pragma unroll
    for (int j = 0; j < KN; ++j) v[j] = ip[j*F + f];
    float bsv = bias ? bias[f] : 0.f;
    #pragma unroll
    for (int k = 0; k < KN; ++k) {
      float s = bsv;
      #pragma unroll
      for (int j = 0; j < KN; ++j) s = fmaf(an[k*KN+j], v[j], s);
      if (relu) s = fmaxf(s, 0.f);
      op[k*F + f] = s;
    }
  }
}

// ---------------- scan step 1: Z, R (both directions) ----------------
__global__ __launch_bounds__(256) void scan1_kernel(
    const float* __restrict__ Pf0, const float* __restrict__ Pf1,
    const float* __restrict__ Pb0, const float* __restrict__ Pb1,
    const float* __restrict__ tfW, const float* __restrict__ tbW,
    const float* __restrict__ Hstf, const float* __restrict__ Hstb,
    const int* __restrict__ rf, const int* __restrict__ rb,
    float* __restrict__ Zbuf, float* __restrict__ Rbuf, int t) {
  int bx = blockIdx.x;
  int fb = bx & 63;
  int g  = (bx >> 6) & 1;
  int d  = bx >> 7;
  int tid = threadIdx.x;
  int fl = tid & 15, sl = tid >> 4;
  int f = fb*16 + fl;
  int reset = d ? rb[t] : rf[t];
  int tt = d ? (T-1-t) : t;
  int prev = d ? (tt+1) : (tt-1);
  const float* H = (d ? Hstb : Hstf) + (size_t)prev*KF;
  const float* P = (d ? (g ? Pb1 : Pb0) : (g ? Pf1 : Pf0)) + (size_t)tt*KF;
  const float* W = (d ? tbW : tfW) + (size_t)g*2*F*F + (size_t)F*F; // bottom half of lW[g]
  float acc[KN];
  #pragma unroll
  for (int k = 0; k < KN; ++k) acc[k] = 0.f;
  if (!reset) {
    for (int j = sl*64; j < sl*64 + 64; ++j) {
      float w = W[(size_t)j*F + f];
      #pragma unroll
      for (int k = 0; k < KN; ++k) acc[k] = fmaf(H[k*F + j], w, acc[k]);
    }
  }
  __shared__ float red[16][KN][17];
  #pragma unroll
  for (int k = 0; k < KN; ++k) red[sl][k][fl] = acc[k];
  __syncthreads();
  if (tid < KN*16) {
    int k = tid >> 4, fl2 = tid & 15;
    int f2 = fb*16 + fl2;
    float s = 0.f;
    #pragma unroll
    for (int s2 = 0; s2 < 16; ++s2) s += red[s2][k][fl2];
    float val = P[k*F + f2] + s;
    val = 1.f / (1.f + expf(-val));
    (g ? Rbuf : Zbuf)[(size_t)d*KF + k*F + f2] = val;
  }
}

// ---------------- scan step 2: Ht, Hn (both directions) ----------------
__global__ __launch_bounds__(256) void scan2_kernel(
    const float* __restrict__ Pf2, const float* __restrict__ Pb2,
    const float* __restrict__ tfW, const float* __restrict__ tbW,
    float* __restrict__ Hstf, float* __restrict__ Hstb,
    const int* __restrict__ rf, const int* __restrict__ rb,
    const float* __restrict__ Zbuf, const float* __restrict__ Rbuf, int t) {
  int bx = blockIdx.x;
  int fb = bx & 63;
  int d  = bx >> 6;
  int tid = threadIdx.x;
  int fl = tid & 15, sl = tid >> 4;
  int f = fb*16 + fl;
  int reset = d ? rb[t] : rf[t];
  int tt = d ? (T-1-t) : t;
  int prev = d ? (tt+1) : (tt-1);
  float* Hst = d ? Hstb : Hstf;
  const float* H = Hst + (size_t)prev*KF;
  const float* P = (d ? Pb2 : Pf2) + (size_t)tt*KF;
  const float* W = (d ? tbW : tfW) + (size_t)2*2*F*F + (size_t)F*F; // bottom half of lW[2]
  const float* Zb_ = Zbuf + (size_t)d*KF;
  const float* Rb_ = Rbuf + (size_t)d*KF;
  float acc[KN];
  #pragma unroll
  for (int k = 0; k < KN; ++k) acc[k] = 0.f;
  if (!reset) {
    for (int j = sl*64; j < sl*64 + 64; ++j) {
      float w = W[(size_t)j*F + f];
      #pragma unroll
      for (int k = 0; k < KN; ++k) acc[k] = fmaf(H[k*F + j] * Rb_[k*F + j], w, acc[k]);
    }
  }
  __shared__ float red[16][KN][17];
  #pragma unroll
  for (int k = 0; k < KN; ++k) red[sl][k][fl] = acc[k];
  __syncthreads();
  if (tid < KN*16) {
    int k = tid >> 4, fl2 = tid & 15;
    int f2 = fb*16 + fl2;
    float s = 0.f;
    #pragma unroll
    for (int s2 = 0; s2 < 16; ++s2) s += red[s2][k][fl2];
    float ht = tanhf(P[k*F + f2] + s);
    float heff = reset ? 0.f : H[k*F + f2];
    float z = Zb_[k*F + f2];
    float hn = z*heff + (1.f - z)*ht;
    Hst[(size_t)tt*KF + k*F + f2] = hn;
  }
}

// ---------------- upsample + sigmoid: (T,K,32,32)->(T,1,K,64,64) ----------------
__global__ void upsample_kernel(const float* __restrict__ Hf, const float* __restrict__ Hb,
                                float* __restrict__ out) {
  __shared__ float h[HF*HF];
  int b = blockIdx.x; // t*KN + k
  int tid = threadIdx.x;
  #pragma unroll
  for (int i = 0; i < 4; ++i) {
    int idx = tid + i*256;
    h[idx] = Hf[(size_t)b*F + idx] + Hb[(size_t)b*F + idx];
  }
  __syncthreads();
  const float r = 31.0f/63.0f;
  float* op = out + (size_t)b*HM*HM;
  #pragma unroll
  for (int i = 0; i < 16; ++i) {
    int idx = tid + i*256;
    int o = idx >> 6, p = idx & 63;
    float co = (float)o * r; int io = (int)floorf(co); int io1 = min(io+1, HF-1); float wo = co - (float)io;
    float cp = (float)p * r; int jp = (int)floorf(cp); int jp1 = min(jp+1, HF-1); float wp = cp - (float)jp;
    float v = (1.f-wo)*((1.f-wp)*h[io*HF+jp]  + wp*h[io*HF+jp1])
            +      wo *((1.f-wp)*h[io1*HF+jp] + wp*h[io1*HF+jp1]);
    op[idx] = 1.f / (1.f + expf(-v));
  }
}

extern "C" void kernel_launch(void* const* d_in, const int* in_sizes, int n_in,
                              void* d_out, int out_size, void* d_ws, size_t ws_size,
                              hipStream_t stream) {
  const float* x      = (const float*)d_in[0];
  const float* A      = (const float*)d_in[1];
  const float* gcn_W  = (const float*)d_in[2];
  const float* gcn_b  = (const float*)d_in[3];
  const float* tf_gW  = (const float*)d_in[4];
  const float* tf_gb  = (const float*)d_in[5];
  const float* tf_lW  = (const float*)d_in[6];
  const float* tf_lb  = (const float*)d_in[7];
  const float* tb_gW  = (const float*)d_in[8];
  const float* tb_gb  = (const float*)d_in[9];
  const float* tb_lW  = (const float*)d_in[10];
  const float* tb_lb  = (const float*)d_in[11];
  const int*   vid    = (const int*)d_in[12];
  float* out = (float*)d_out;

  float* ws = (float*)d_ws;
  float* An = ws;                  // 196 floats
  int* rf = (int*)(ws + 256);      // 128 ints
  int* rb = (int*)(ws + 512);      // 128 ints
  const size_t SEG = (size_t)TK * F;  // 1,835,008 floats
  float* feat = ws + 4096;
  float* tmpA = feat + SEG;
  float* tmpB = tmpA + SEG;
  float* p = tmpB + SEG;
  float* Pf[3]; float* Pb[3];
  for (int c = 0; c < 3; ++c) { Pf[c] = p; p += SEG; }
  for (int c = 0; c < 3; ++c) { Pb[c] = p; p += SEG; }
  float* Hstf = p; p += SEG;
  float* Hstb = p; p += SEG;
  float* Zbuf = p; p += 2*KF;
  float* Rbuf = p; p += 2*KF;

  prep_kernel<<<1, 256, 0, stream>>>(A, vid, An, rf, rb);
  downsample_kernel<<<TK, 256, 0, stream>>>(x, feat);

  dim3 ggrid(F/BN, TK/BM); // (16, 14)
  // GCN layers
  for (int l = 0; l < 2; ++l) {
    gemm_kernel<<<ggrid, 256, 0, stream>>>(feat, F, gcn_W + (size_t)l*F*F, F, nullptr, tmpA, F, F);
    anmix_kernel<<<T, 256, 0, stream>>>(tmpA, An, gcn_b + (size_t)l*F, feat, 1);
  }
  // Per-direction input-side precompute: conv_c and P_c for all t
  for (int d = 0; d < 2; ++d) {
    const float* gW = d ? tb_gW : tf_gW;
    const float* gb = d ? tb_gb : tf_gb;
    const float* lW = d ? tb_lW : tf_lW;
    const float* lb = d ? tb_lb : tf_lb;
    float** Pd = d ? Pb : Pf;
    for (int c = 0; c < 3; ++c) {
      gemm_kernel<<<ggrid, 256, 0, stream>>>(feat, F, gW + (size_t)c*F*F, F, nullptr, tmpA, F, F);
      anmix_kernel<<<T, 256, 0, stream>>>(tmpA, An, gb + (size_t)c*F, tmpB, 0);
      gemm_kernel<<<ggrid, 256, 0, stream>>>(tmpB, F, lW + (size_t)c*2*F*F, F, lb + (size_t)c*F, Pd[c], F, F);
    }
  }
  // Sequential GRU scan (fwd + bwd fused per launch)
  for (int t = 0; t < T; ++t) {
    scan1_kernel<<<256, 256, 0, stream>>>(Pf[0], Pf[1], Pb[0], Pb[1], tf_lW, tb_lW,
                                          Hstf, Hstb, rf, rb, Zbuf, Rbuf, t);
    scan2_kernel<<<128, 256, 0, stream>>>(Pf[2], Pb[2], tf_lW, tb_lW,
                                          Hstf, Hstb, rf, rb, Zbuf, Rbuf, t);
  }
  upsample_kernel<<<TK, 256, 0, stream>>>(Hstf, Hstb, out);
}

// Round 2
// 7353.888 us; speedup vs baseline: 1.2063x; 1.2063x over previous
//
#include <hip/hip_runtime.h>
#include <hip/hip_bf16.h>
#include <math.h>

#define T 128
#define KN 14      // graph nodes
#define HM 64
#define HF 32
#define F 1024
#define TK (T*KN)   // 1792
#define KF (KN*F)   // 14336

typedef __attribute__((ext_vector_type(8))) short bf16x8;
typedef __attribute__((ext_vector_type(4))) float f32x4;

// ---------------- prep: An (gcn_norm) + reset flags ----------------
__global__ void prep_kernel(const float* __restrict__ A, const int* __restrict__ vid,
                            float* __restrict__ An, int* __restrict__ rf, int* __restrict__ rb) {
  __shared__ float dinv[KN];
  int tid = threadIdx.x;
  if (tid < KN) {
    float s = 0.f;
    for (int j = 0; j < KN; ++j) {
      float ab = (A[tid*KN + j] != 0.f) ? 1.f : 0.f;
      if (j == tid) ab += 1.f;
      s += ab;
    }
    dinv[tid] = 1.0f / sqrtf(s);
  }
  __syncthreads();
  if (tid < KN*KN) {
    int i = tid / KN, j = tid % KN;
    float ab = (A[i*KN + j] != 0.f) ? 1.f : 0.f;
    if (i == j) ab += 1.f;
    An[tid] = dinv[i] * ab * dinv[j];
  }
  if (tid < T) {
    rf[tid] = (tid == 0) || (vid[tid] != vid[tid-1]);
    rb[tid] = (tid == 0) || (vid[T-1-tid] != vid[T-tid]);
  }
}

// ---------------- downsample: x (T,K,64,64) -> feat_bf (T,K,1024) ----------------
__global__ void downsample_kernel(const float* __restrict__ x, __hip_bfloat16* __restrict__ feat) {
  __shared__ float xt[HM*HM];
  int b = blockIdx.x; // t*KN + k
  const float* xp = x + (size_t)b*HM*HM;
  int tid = threadIdx.x;
  #pragma unroll
  for (int i = 0; i < 4; ++i)
    ((float4*)xt)[tid + i*256] = ((const float4*)xp)[tid + i*256];
  __syncthreads();
  const float r = 63.0f/31.0f;
  __hip_bfloat16* fp = feat + (size_t)b*F;
  #pragma unroll
  for (int i = 0; i < 4; ++i) {
    int idx = tid + i*256;
    int o = idx >> 5, p = idx & 31;
    float co = (float)o * r; int io = (int)floorf(co); int io1 = min(io+1, HM-1); float wo = co - (float)io;
    float cp = (float)p * r; int jp = (int)floorf(cp); int jp1 = min(jp+1, HM-1); float wp = cp - (float)jp;
    float v = (1.f-wo)*((1.f-wp)*xt[io*HM+jp]  + wp*xt[io*HM+jp1])
            +      wo *((1.f-wp)*xt[io1*HM+jp] + wp*xt[io1*HM+jp1]);
    fp[idx] = __float2bfloat16(v);
  }
}

// ---------------- convert+transpose one FxF fp32 block -> bf16 (dst = src^T) ----------------
__global__ void convt_kernel(const float* __restrict__ src, __hip_bfloat16* __restrict__ dst) {
  __shared__ float tile[32][33];
  int bx = blockIdx.x, by = blockIdx.y;
  int tx = threadIdx.x & 31, ty = threadIdx.x >> 5; // ty 0..7
  #pragma unroll
  for (int i = 0; i < 4; ++i)
    tile[ty + i*8][tx] = src[(size_t)(by*32 + ty + i*8)*F + bx*32 + tx];
  __syncthreads();
  #pragma unroll
  for (int i = 0; i < 4; ++i)
    dst[(size_t)(bx*32 + ty + i*8)*F + by*32 + tx] = __float2bfloat16(tile[tx][ty + i*8]);
}

// ---------------- bf16 MFMA GEMM: C(M,N) = A(M,K) @ Bt(N,K)^T (+bias) ----------------
// A: M x 1024 bf16 row-major; Bt: N x 1024 bf16 row-major (pre-transposed weights)
// OUT_BF16: 1 -> bf16 output, 0 -> fp32 output
template<int OUT_BF16>
__global__ __launch_bounds__(256) void gemm_mfma(
    const __hip_bfloat16* __restrict__ A, const __hip_bfloat16* __restrict__ Bt,
    const float* __restrict__ bias, void* __restrict__ C, int ldc) {
  const int Kd = 1024;
  __shared__ short As[128][40]; // 32 used + pad
  __shared__ short Bs[128][40];
  int tid = threadIdx.x;
  int wave = tid >> 6, lane = tid & 63;
  int mBase = blockIdx.y * 128, nBase = blockIdx.x * 128;
  int srow = tid >> 2;          // 0..63
  int scol = (tid & 3) * 8;     // 0,8,16,24
  int mW = (wave >> 1) * 64, nW = (wave & 1) * 64;
  int fr = lane & 15;
  int fk = (lane >> 4) * 8;
  f32x4 acc[4][4];
  #pragma unroll
  for (int i = 0; i < 4; ++i)
    #pragma unroll
    for (int j = 0; j < 4; ++j)
      acc[i][j] = (f32x4){0.f, 0.f, 0.f, 0.f};
  for (int k0 = 0; k0 < Kd; k0 += 32) {
    float4 a0 = *(const float4*)(A  + (size_t)(mBase + srow)*Kd + k0 + scol);
    float4 a1 = *(const float4*)(A  + (size_t)(mBase + srow + 64)*Kd + k0 + scol);
    float4 b0 = *(const float4*)(Bt + (size_t)(nBase + srow)*Kd + k0 + scol);
    float4 b1 = *(const float4*)(Bt + (size_t)(nBase + srow + 64)*Kd + k0 + scol);
    __syncthreads();
    *(float4*)&As[srow][scol] = a0;
    *(float4*)&As[srow+64][scol] = a1;
    *(float4*)&Bs[srow][scol] = b0;
    *(float4*)&Bs[srow+64][scol] = b1;
    __syncthreads();
    bf16x8 af[4], bfr[4];
    #pragma unroll
    for (int i = 0; i < 4; ++i) af[i]  = *(const bf16x8*)&As[mW + i*16 + fr][fk];
    #pragma unroll
    for (int j = 0; j < 4; ++j) bfr[j] = *(const bf16x8*)&Bs[nW + j*16 + fr][fk];
    #pragma unroll
    for (int i = 0; i < 4; ++i)
      #pragma unroll
      for (int j = 0; j < 4; ++j)
        acc[i][j] = __builtin_amdgcn_mfma_f32_16x16x32_bf16(af[i], bfr[j], acc[i][j], 0, 0, 0);
  }
  int rq = (lane >> 4) * 4;
  int cl = lane & 15;
  float bv[4];
  #pragma unroll
  for (int j = 0; j < 4; ++j) bv[j] = bias ? bias[nBase + nW + j*16 + cl] : 0.f;
  #pragma unroll
  for (int i = 0; i < 4; ++i) {
    #pragma unroll
    for (int r = 0; r < 4; ++r) {
      int row = mBase + mW + i*16 + rq + r;
      #pragma unroll
      for (int j = 0; j < 4; ++j) {
        int col = nBase + nW + j*16 + cl;
        float v = acc[i][j][r] + bv[j];
        if (OUT_BF16)
          ((__hip_bfloat16*)C)[(size_t)row*ldc + col] = __float2bfloat16(v);
        else
          ((float*)C)[(size_t)row*ldc + col] = v;
      }
    }
  }
}

// ---------------- An-mix over node dim (+bias, opt relu), bf16 in/out ----------------
__global__ void anmix_kernel(const __hip_bfloat16* __restrict__ in, const float* __restrict__ An,
                             const float* __restrict__ bias, __hip_bfloat16* __restrict__ out, int relu) {
  __shared__ float an[KN*KN];
  int t = blockIdx.x, tid = threadIdx.x;
  if (tid < KN*KN) an[tid] = An[tid];
  __syncthreads();
  const __hip_bfloat16* ip = in + (size_t)t*KF;
  __hip_bfloat16* op = out + (size_t)t*KF;
  #pragma unroll
  for (int i = 0; i < 4; ++i) {
    int f = tid + i*256;
    float v[KN];
    #pragma unroll
    for (int j = 0; j < KN; ++j) v[j] = __bfloat162float(ip[j*F + f]);
    float bsv = bias ? bias[f] : 0.f;
    #pragma unroll
    for (int k = 0; k < KN; ++k) {
      float s = bsv;
      #pragma unroll
      for (int j = 0; j < KN; ++j) s = fmaf(an[k*KN+j], v[j], s);
      if (relu) s = fmaxf(s, 0.f);
      op[k*F + f] = __float2bfloat16(s);
    }
  }
}

// ---------------- scan step 1: Z, R (both directions) ----------------
__global__ __launch_bounds__(256) void scan1_kernel(
    const float* __restrict__ Pf0, const float* __restrict__ Pf1,
    const float* __restrict__ Pb0, const float* __restrict__ Pb1,
    const float* __restrict__ tfW, const float* __restrict__ tbW,
    const float* __restrict__ Hstf, const float* __restrict__ Hstb,
    const int* __restrict__ rf, const int* __restrict__ rb,
    float* __restrict__ Zbuf, float* __restrict__ Rbuf, int t) {
  int bx = blockIdx.x;
  int fb = bx & 63;
  int g  = (bx >> 6) & 1;
  int d  = bx >> 7;
  int tid = threadIdx.x;
  int fl = tid & 15, sl = tid >> 4;
  int f = fb*16 + fl;
  int reset = d ? rb[t] : rf[t];
  int tt = d ? (T-1-t) : t;
  int prev = d ? (tt+1) : (tt-1);
  const float* H = (d ? Hstb : Hstf) + (size_t)prev*KF;
  const float* P = (d ? (g ? Pb1 : Pb0) : (g ? Pf1 : Pf0)) + (size_t)tt*KF;
  const float* W = (d ? tbW : tfW) + (size_t)g*2*F*F + (size_t)F*F; // bottom half of lW[g]
  float acc[KN];
  #pragma unroll
  for (int k = 0; k < KN; ++k) acc[k] = 0.f;
  if (!reset) {
    for (int j = sl*64; j < sl*64 + 64; ++j) {
      float w = W[(size_t)j*F + f];
      #pragma unroll
      for (int k = 0; k < KN; ++k) acc[k] = fmaf(H[k*F + j], w, acc[k]);
    }
  }
  __shared__ float red[16][KN][17];
  #pragma unroll
  for (int k = 0; k < KN; ++k) red[sl][k][fl] = acc[k];
  __syncthreads();
  if (tid < KN*16) {
    int k = tid >> 4, fl2 = tid & 15;
    int f2 = fb*16 + fl2;
    float s = 0.f;
    #pragma unroll
    for (int s2 = 0; s2 < 16; ++s2) s += red[s2][k][fl2];
    float val = P[k*F + f2] + s;
    val = 1.f / (1.f + expf(-val));
    (g ? Rbuf : Zbuf)[(size_t)d*KF + k*F + f2] = val;
  }
}

// ---------------- scan step 2: Ht, Hn (both directions) ----------------
__global__ __launch_bounds__(256) void scan2_kernel(
    const float* __restrict__ Pf2, const float* __restrict__ Pb2,
    const float* __restrict__ tfW, const float* __restrict__ tbW,
    float* __restrict__ Hstf, float* __restrict__ Hstb,
    const int* __restrict__ rf, const int* __restrict__ rb,
    const float* __restrict__ Zbuf, const float* __restrict__ Rbuf, int t) {
  int bx = blockIdx.x;
  int fb = bx & 63;
  int d  = bx >> 6;
  int tid = threadIdx.x;
  int fl = tid & 15, sl = tid >> 4;
  int f = fb*16 + fl;
  int reset = d ? rb[t] : rf[t];
  int tt = d ? (T-1-t) : t;
  int prev = d ? (tt+1) : (tt-1);
  float* Hst = d ? Hstb : Hstf;
  const float* H = Hst + (size_t)prev*KF;
  const float* P = (d ? Pb2 : Pf2) + (size_t)tt*KF;
  const float* W = (d ? tbW : tfW) + (size_t)2*2*F*F + (size_t)F*F; // bottom half of lW[2]
  const float* Zb_ = Zbuf + (size_t)d*KF;
  const float* Rb_ = Rbuf + (size_t)d*KF;
  float acc[KN];
  #pragma unroll
  for (int k = 0; k < KN; ++k) acc[k] = 0.f;
  if (!reset) {
    for (int j = sl*64; j < sl*64 + 64; ++j) {
      float w = W[(size_t)j*F + f];
      #pragma unroll
      for (int k = 0; k < KN; ++k) acc[k] = fmaf(H[k*F + j] * Rb_[k*F + j], w, acc[k]);
    }
  }
  __shared__ float red[16][KN][17];
  #pragma unroll
  for (int k = 0; k < KN; ++k) red[sl][k][fl] = acc[k];
  __syncthreads();
  if (tid < KN*16) {
    int k = tid >> 4, fl2 = tid & 15;
    int f2 = fb*16 + fl2;
    float s = 0.f;
    #pragma unroll
    for (int s2 = 0; s2 < 16; ++s2) s += red[s2][k][fl2];
    float ht = tanhf(P[k*F + f2] + s);
    float heff = reset ? 0.f : H[k*F + f2];
    float z = Zb_[k*F + f2];
    float hn = z*heff + (1.f - z)*ht;
    Hst[(size_t)tt*KF + k*F + f2] = hn;
  }
}

// ---------------- upsample + sigmoid: (T,K,32,32)->(T,1,K,64,64) ----------------
__global__ void upsample_kernel(const float* __restrict__ Hf, const float* __restrict__ Hb,
                                float* __restrict__ out) {
  __shared__ float h[HF*HF];
  int b = blockIdx.x; // t*KN + k
  int tid = threadIdx.x;
  #pragma unroll
  for (int i = 0; i < 4; ++i) {
    int idx = tid + i*256;
    h[idx] = Hf[(size_t)b*F + idx] + Hb[(size_t)b*F + idx];
  }
  __syncthreads();
  const float r = 31.0f/63.0f;
  float* op = out + (size_t)b*HM*HM;
  #pragma unroll
  for (int i = 0; i < 16; ++i) {
    int idx = tid + i*256;
    int o = idx >> 6, p = idx & 63;
    float co = (float)o * r; int io = (int)floorf(co); int io1 = min(io+1, HF-1); float wo = co - (float)io;
    float cp = (float)p * r; int jp = (int)floorf(cp); int jp1 = min(jp+1, HF-1); float wp = cp - (float)jp;
    float v = (1.f-wo)*((1.f-wp)*h[io*HF+jp]  + wp*h[io*HF+jp1])
            +      wo *((1.f-wp)*h[io1*HF+jp] + wp*h[io1*HF+jp1]);
    op[idx] = 1.f / (1.f + expf(-v));
  }
}

extern "C" void kernel_launch(void* const* d_in, const int* in_sizes, int n_in,
                              void* d_out, int out_size, void* d_ws, size_t ws_size,
                              hipStream_t stream) {
  const float* x      = (const float*)d_in[0];
  const float* A      = (const float*)d_in[1];
  const float* gcn_W  = (const float*)d_in[2];
  const float* gcn_b  = (const float*)d_in[3];
  const float* tf_gW  = (const float*)d_in[4];
  const float* tf_gb  = (const float*)d_in[5];
  const float* tf_lW  = (const float*)d_in[6];
  const float* tf_lb  = (const float*)d_in[7];
  const float* tb_gW  = (const float*)d_in[8];
  const float* tb_gb  = (const float*)d_in[9];
  const float* tb_lW  = (const float*)d_in[10];
  const float* tb_lb  = (const float*)d_in[11];
  const int*   vid    = (const int*)d_in[12];
  float* out = (float*)d_out;

  float* ws = (float*)d_ws;
  float* An = ws;                  // 196 floats
  int* rf = (int*)(ws + 256);      // 128 ints
  int* rb = (int*)(ws + 512);      // 128 ints
  const size_t SEG = (size_t)TK * F;  // 1,835,008
  float* p = ws + 1024;
  float* Pf[3]; float* Pb[3];
  for (int c = 0; c < 3; ++c) { Pf[c] = p; p += SEG; }
  for (int c = 0; c < 3; ++c) { Pb[c] = p; p += SEG; }
  float* Hstf = p; p += SEG;
  float* Hstb = p; p += SEG;
  float* Zbuf = p; p += 2*KF;
  float* Rbuf = p; p += 2*KF;
  // bf16 region
  __hip_bfloat16* bp = (__hip_bfloat16*)p;
  __hip_bfloat16* feat_bf = bp; bp += SEG;
  __hip_bfloat16* tmpA_bf = bp; bp += SEG;
  __hip_bfloat16* tmpB_bf = bp; bp += SEG;
  const size_t WSEG = (size_t)F*F;
  __hip_bfloat16* wT_gcn[2];
  __hip_bfloat16* wT_g[2][3];
  __hip_bfloat16* wT_l[2][3];
  for (int l = 0; l < 2; ++l) { wT_gcn[l] = bp; bp += WSEG; }
  for (int d = 0; d < 2; ++d)
    for (int c = 0; c < 3; ++c) { wT_g[d][c] = bp; bp += WSEG; }
  for (int d = 0; d < 2; ++d)
    for (int c = 0; c < 3; ++c) { wT_l[d][c] = bp; bp += WSEG; }

  prep_kernel<<<1, 256, 0, stream>>>(A, vid, An, rf, rb);
  downsample_kernel<<<TK, 256, 0, stream>>>(x, feat_bf);

  // weight convert+transpose (src blocks are contiguous FxF fp32)
  dim3 tgrid(32, 32);
  for (int l = 0; l < 2; ++l)
    convt_kernel<<<tgrid, 256, 0, stream>>>(gcn_W + (size_t)l*WSEG, wT_gcn[l]);
  for (int c = 0; c < 3; ++c) {
    convt_kernel<<<tgrid, 256, 0, stream>>>(tf_gW + (size_t)c*WSEG, wT_g[0][c]);
    convt_kernel<<<tgrid, 256, 0, stream>>>(tb_gW + (size_t)c*WSEG, wT_g[1][c]);
    convt_kernel<<<tgrid, 256, 0, stream>>>(tf_lW + (size_t)c*2*WSEG, wT_l[0][c]); // top F rows
    convt_kernel<<<tgrid, 256, 0, stream>>>(tb_lW + (size_t)c*2*WSEG, wT_l[1][c]);
  }

  dim3 ggrid(F/128, TK/128); // (8, 14)
  // GCN layers
  for (int l = 0; l < 2; ++l) {
    gemm_mfma<1><<<ggrid, 256, 0, stream>>>(feat_bf, wT_gcn[l], nullptr, tmpA_bf, F);
    anmix_kernel<<<T, 256, 0, stream>>>(tmpA_bf, An, gcn_b + (size_t)l*F, feat_bf, 1);
  }
  // Per-direction input-side precompute: conv_c then P_c for all t
  for (int d = 0; d < 2; ++d) {
    const float* gb = d ? tb_gb : tf_gb;
    const float* lb = d ? tb_lb : tf_lb;
    float** Pd = d ? Pb : Pf;
    for (int c = 0; c < 3; ++c) {
      gemm_mfma<1><<<ggrid, 256, 0, stream>>>(feat_bf, wT_g[d][c], nullptr, tmpA_bf, F);
      anmix_kernel<<<T, 256, 0, stream>>>(tmpA_bf, An, gb + (size_t)c*F, tmpB_bf, 0);
      gemm_mfma<0><<<ggrid, 256, 0, stream>>>(tmpB_bf, wT_l[d][c], lb + (size_t)c*F, Pd[c], F);
    }
  }
  // Sequential GRU scan (fwd + bwd fused per launch)
  for (int t = 0; t < T; ++t) {
    scan1_kernel<<<256, 256, 0, stream>>>(Pf[0], Pf[1], Pb[0], Pb[1], tf_lW, tb_lW,
                                          Hstf, Hstb, rf, rb, Zbuf, Rbuf, t);
    scan2_kernel<<<128, 256, 0, stream>>>(Pf[2], Pb[2], tf_lW, tb_lW,
                                          Hstf, Hstb, rf, rb, Zbuf, Rbuf, t);
  }
  upsample_kernel<<<TK, 256, 0, stream>>>(Hstf, Hstb, out);
}

// Round 3
// 3187.824 us; speedup vs baseline: 2.7828x; 2.3069x over previous
//
#include <hip/hip_runtime.h>
#include <hip/hip_bf16.h>
#include <math.h>

#define T 128
#define KN 14      // graph nodes
#define HM 64
#define HF 32
#define F 1024
#define TK (T*KN)   // 1792
#define KF (KN*F)   // 14336

typedef __attribute__((ext_vector_type(8))) short bf16x8;
typedef __attribute__((ext_vector_type(4))) float f32x4;

static __device__ __forceinline__ short f2bs(float f) {
  __hip_bfloat16 h = __float2bfloat16(f);
  return *reinterpret_cast<short*>(&h);
}

// ---------------- prep: An (gcn_norm) + reset flags ----------------
__global__ void prep_kernel(const float* __restrict__ A, const int* __restrict__ vid,
                            float* __restrict__ An, int* __restrict__ rf, int* __restrict__ rb) {
  __shared__ float dinv[KN];
  int tid = threadIdx.x;
  if (tid < KN) {
    float s = 0.f;
    for (int j = 0; j < KN; ++j) {
      float ab = (A[tid*KN + j] != 0.f) ? 1.f : 0.f;
      if (j == tid) ab += 1.f;
      s += ab;
    }
    dinv[tid] = 1.0f / sqrtf(s);
  }
  __syncthreads();
  if (tid < KN*KN) {
    int i = tid / KN, j = tid % KN;
    float ab = (A[i*KN + j] != 0.f) ? 1.f : 0.f;
    if (i == j) ab += 1.f;
    An[tid] = dinv[i] * ab * dinv[j];
  }
  if (tid < T) {
    rf[tid] = (tid == 0) || (vid[tid] != vid[tid-1]);
    rb[tid] = (tid == 0) || (vid[T-1-tid] != vid[T-tid]);
  }
}

// ---------------- downsample: x (T,K,64,64) -> feat_bf (T,K,1024) ----------------
__global__ void downsample_kernel(const float* __restrict__ x, __hip_bfloat16* __restrict__ feat) {
  __shared__ float xt[HM*HM];
  int b = blockIdx.x; // t*KN + k
  const float* xp = x + (size_t)b*HM*HM;
  int tid = threadIdx.x;
  #pragma unroll
  for (int i = 0; i < 4; ++i)
    ((float4*)xt)[tid + i*256] = ((const float4*)xp)[tid + i*256];
  __syncthreads();
  const float r = 63.0f/31.0f;
  __hip_bfloat16* fp = feat + (size_t)b*F;
  #pragma unroll
  for (int i = 0; i < 4; ++i) {
    int idx = tid + i*256;
    int o = idx >> 5, p = idx & 31;
    float co = (float)o * r; int io = (int)floorf(co); int io1 = min(io+1, HM-1); float wo = co - (float)io;
    float cp = (float)p * r; int jp = (int)floorf(cp); int jp1 = min(jp+1, HM-1); float wp = cp - (float)jp;
    float v = (1.f-wo)*((1.f-wp)*xt[io*HM+jp]  + wp*xt[io*HM+jp1])
            +      wo *((1.f-wp)*xt[io1*HM+jp] + wp*xt[io1*HM+jp1]);
    fp[idx] = __float2bfloat16(v);
  }
}

// ---------------- convert+transpose one FxF fp32 block -> bf16 (dst = src^T) ----------------
__global__ void convt_kernel(const float* __restrict__ src, __hip_bfloat16* __restrict__ dst) {
  __shared__ float tile[32][33];
  int bx = blockIdx.x, by = blockIdx.y;
  int tx = threadIdx.x & 31, ty = threadIdx.x >> 5; // ty 0..7
  #pragma unroll
  for (int i = 0; i < 4; ++i)
    tile[ty + i*8][tx] = src[(size_t)(by*32 + ty + i*8)*F + bx*32 + tx];
  __syncthreads();
  #pragma unroll
  for (int i = 0; i < 4; ++i)
    dst[(size_t)(bx*32 + ty + i*8)*F + by*32 + tx] = __float2bfloat16(tile[tx][ty + i*8]);
}

// ---------------- bf16 MFMA GEMM: C(M,N) = A(M,K) @ Bt(N,K)^T (+bias) ----------------
template<int OUT_BF16>
__global__ __launch_bounds__(256) void gemm_mfma(
    const __hip_bfloat16* __restrict__ A, const __hip_bfloat16* __restrict__ Bt,
    const float* __restrict__ bias, void* __restrict__ C, int ldc) {
  const int Kd = 1024;
  __shared__ short As[128][40]; // 32 used + pad
  __shared__ short Bs[128][40];
  int tid = threadIdx.x;
  int wave = tid >> 6, lane = tid & 63;
  int mBase = blockIdx.y * 128, nBase = blockIdx.x * 128;
  int srow = tid >> 2;          // 0..63
  int scol = (tid & 3) * 8;     // 0,8,16,24
  int mW = (wave >> 1) * 64, nW = (wave & 1) * 64;
  int fr = lane & 15;
  int fk = (lane >> 4) * 8;
  f32x4 acc[4][4];
  #pragma unroll
  for (int i = 0; i < 4; ++i)
    #pragma unroll
    for (int j = 0; j < 4; ++j)
      acc[i][j] = (f32x4){0.f, 0.f, 0.f, 0.f};
  for (int k0 = 0; k0 < Kd; k0 += 32) {
    float4 a0 = *(const float4*)(A  + (size_t)(mBase + srow)*Kd + k0 + scol);
    float4 a1 = *(const float4*)(A  + (size_t)(mBase + srow + 64)*Kd + k0 + scol);
    float4 b0 = *(const float4*)(Bt + (size_t)(nBase + srow)*Kd + k0 + scol);
    float4 b1 = *(const float4*)(Bt + (size_t)(nBase + srow + 64)*Kd + k0 + scol);
    __syncthreads();
    *(float4*)&As[srow][scol] = a0;
    *(float4*)&As[srow+64][scol] = a1;
    *(float4*)&Bs[srow][scol] = b0;
    *(float4*)&Bs[srow+64][scol] = b1;
    __syncthreads();
    bf16x8 af[4], bfr[4];
    #pragma unroll
    for (int i = 0; i < 4; ++i) af[i]  = *(const bf16x8*)&As[mW + i*16 + fr][fk];
    #pragma unroll
    for (int j = 0; j < 4; ++j) bfr[j] = *(const bf16x8*)&Bs[nW + j*16 + fr][fk];
    #pragma unroll
    for (int i = 0; i < 4; ++i)
      #pragma unroll
      for (int j = 0; j < 4; ++j)
        acc[i][j] = __builtin_amdgcn_mfma_f32_16x16x32_bf16(af[i], bfr[j], acc[i][j], 0, 0, 0);
  }
  int rq = (lane >> 4) * 4;
  int cl = lane & 15;
  float bv[4];
  #pragma unroll
  for (int j = 0; j < 4; ++j) bv[j] = bias ? bias[nBase + nW + j*16 + cl] : 0.f;
  #pragma unroll
  for (int i = 0; i < 4; ++i) {
    #pragma unroll
    for (int r = 0; r < 4; ++r) {
      int row = mBase + mW + i*16 + rq + r;
      #pragma unroll
      for (int j = 0; j < 4; ++j) {
        int col = nBase + nW + j*16 + cl;
        float v = acc[i][j][r] + bv[j];
        if (OUT_BF16)
          ((__hip_bfloat16*)C)[(size_t)row*ldc + col] = __float2bfloat16(v);
        else
          ((float*)C)[(size_t)row*ldc + col] = v;
      }
    }
  }
}

// ---------------- An-mix over node dim (+bias, opt relu), bf16 in/out ----------------
__global__ void anmix_kernel(const __hip_bfloat16* __restrict__ in, const float* __restrict__ An,
                             const float* __restrict__ bias, __hip_bfloat16* __restrict__ out, int relu) {
  __shared__ float an[KN*KN];
  int t = blockIdx.x, tid = threadIdx.x;
  if (tid < KN*KN) an[tid] = An[tid];
  __syncthreads();
  const __hip_bfloat16* ip = in + (size_t)t*KF;
  __hip_bfloat16* op = out + (size_t)t*KF;
  #pragma unroll
  for (int i = 0; i < 4; ++i) {
    int f = tid + i*256;
    float v[KN];
    #pragma unroll
    for (int j = 0; j < KN; ++j) v[j] = __bfloat162float(ip[j*F + f]);
    float bsv = bias ? bias[f] : 0.f;
    #pragma unroll
    for (int k = 0; k < KN; ++k) {
      float s = bsv;
      #pragma unroll
      for (int j = 0; j < KN; ++j) s = fmaf(an[k*KN+j], v[j], s);
      if (relu) s = fmaxf(s, 0.f);
      op[k*F + f] = __float2bfloat16(s);
    }
  }
}

// ---------------- scan step A: Z, R via MFMA (both dirs, both gates) ----------------
// wScan layout: [d][g] each F*F bf16, row n (output col), col j (H feature): W^T
__global__ __launch_bounds__(256) void scanA_kernel(
    const float* __restrict__ Hstf, const float* __restrict__ Hstb,
    const short* __restrict__ wScan,
    const float* __restrict__ Pf0, const float* __restrict__ Pf1,
    const float* __restrict__ Pb0, const float* __restrict__ Pb1,
    const int* __restrict__ rf, const int* __restrict__ rb,
    float* __restrict__ Zbuf, float* __restrict__ Rbuf, int t) {
  int bx = blockIdx.x;     // 0..31
  int d = bx >> 4;
  int cb = bx & 15;        // 64-col block
  int tid = threadIdx.x;
  int wave = tid >> 6, lane = tid & 63;
  int reset = d ? rb[t] : rf[t];
  int tt = d ? (T-1-t) : t;
  int prev = d ? (tt+1) : (tt-1);
  const float* H = (d ? Hstb : Hstf) + (size_t)prev*KF;

  __shared__ short Ash[16][1032];
  f32x4 accZ = (f32x4){0.f,0.f,0.f,0.f};
  f32x4 accR = (f32x4){0.f,0.f,0.f,0.f};
  int cl = lane & 15;
  int kq = (lane >> 4) * 8;

  if (!reset) {
    // zero pad rows 14,15
    #pragma unroll
    for (int i = 0; i < 8; ++i) {
      int e = tid + i*256;          // 0..2047
      Ash[14 + (e >> 10)][e & 1023] = 0;
    }
    // stage H (14x1024 fp32) -> bf16 LDS
    #pragma unroll
    for (int i = 0; i < 14; ++i) {
      int e4 = tid + i*256;         // float4 index 0..3583
      float4 v = ((const float4*)H)[e4];
      int e = e4 * 4;
      int row = e >> 10, col = e & 1023;
      short4 s; s.x = f2bs(v.x); s.y = f2bs(v.y); s.z = f2bs(v.z); s.w = f2bs(v.w);
      *(short4*)&Ash[row][col] = s;
    }
    __syncthreads();
    int colRow = cb*64 + wave*16 + cl;
    const short* W0 = wScan + ((size_t)(d*3 + 0))*F*F + (size_t)colRow*F + kq;
    const short* W1 = wScan + ((size_t)(d*3 + 1))*F*F + (size_t)colRow*F + kq;
    #pragma unroll 8
    for (int kc = 0; kc < 32; ++kc) {
      bf16x8 a  = *(const bf16x8*)&Ash[cl][kc*32 + kq];
      bf16x8 b0 = *(const bf16x8*)(W0 + kc*32);
      bf16x8 b1 = *(const bf16x8*)(W1 + kc*32);
      accZ = __builtin_amdgcn_mfma_f32_16x16x32_bf16(a, b0, accZ, 0, 0, 0);
      accR = __builtin_amdgcn_mfma_f32_16x16x32_bf16(a, b1, accR, 0, 0, 0);
    }
  }
  int rq = (lane >> 4) * 4;
  int colg = cb*64 + wave*16 + cl;
  const float* P0 = (d ? Pb0 : Pf0) + (size_t)tt*KF;
  const float* P1 = (d ? Pb1 : Pf1) + (size_t)tt*KF;
  float* Z = Zbuf + (size_t)d*KF;
  float* R = Rbuf + (size_t)d*KF;
  #pragma unroll
  for (int r = 0; r < 4; ++r) {
    int node = rq + r;
    if (node < KN) {
      float z = 1.f / (1.f + expf(-(P0[node*F + colg] + accZ[r])));
      float rr = 1.f / (1.f + expf(-(P1[node*F + colg] + accR[r])));
      Z[node*F + colg] = z;
      R[node*F + colg] = rr;
    }
  }
}

// ---------------- scan step B: Ht, Hn via MFMA (both dirs) ----------------
__global__ __launch_bounds__(256) void scanB_kernel(
    float* __restrict__ Hstf, float* __restrict__ Hstb,
    const short* __restrict__ wScan,
    const float* __restrict__ Pf2, const float* __restrict__ Pb2,
    const int* __restrict__ rf, const int* __restrict__ rb,
    const float* __restrict__ Zbuf, const float* __restrict__ Rbuf, int t) {
  int bx = blockIdx.x;     // 0..31
  int d = bx >> 4;
  int cb = bx & 15;
  int tid = threadIdx.x;
  int wave = tid >> 6, lane = tid & 63;
  int reset = d ? rb[t] : rf[t];
  int tt = d ? (T-1-t) : t;
  int prev = d ? (tt+1) : (tt-1);
  float* Hst = d ? Hstb : Hstf;
  const float* H = Hst + (size_t)prev*KF;
  const float* Rb = Rbuf + (size_t)d*KF;
  const float* Zb = Zbuf + (size_t)d*KF;

  __shared__ short Ash[16][1032];
  f32x4 acc = (f32x4){0.f,0.f,0.f,0.f};
  int cl = lane & 15;
  int kq = (lane >> 4) * 8;

  if (!reset) {
    #pragma unroll
    for (int i = 0; i < 8; ++i) {
      int e = tid + i*256;
      Ash[14 + (e >> 10)][e & 1023] = 0;
    }
    #pragma unroll
    for (int i = 0; i < 14; ++i) {
      int e4 = tid + i*256;
      float4 v = ((const float4*)H)[e4];
      float4 rv = ((const float4*)Rb)[e4];
      int e = e4 * 4;
      int row = e >> 10, col = e & 1023;
      short4 s;
      s.x = f2bs(v.x * rv.x); s.y = f2bs(v.y * rv.y);
      s.z = f2bs(v.z * rv.z); s.w = f2bs(v.w * rv.w);
      *(short4*)&Ash[row][col] = s;
    }
    __syncthreads();
    int colRow = cb*64 + wave*16 + cl;
    const short* W2 = wScan + ((size_t)(d*3 + 2))*F*F + (size_t)colRow*F + kq;
    #pragma unroll 8
    for (int kc = 0; kc < 32; ++kc) {
      bf16x8 a = *(const bf16x8*)&Ash[cl][kc*32 + kq];
      bf16x8 b = *(const bf16x8*)(W2 + kc*32);
      acc = __builtin_amdgcn_mfma_f32_16x16x32_bf16(a, b, acc, 0, 0, 0);
    }
  }
  int rq = (lane >> 4) * 4;
  int colg = cb*64 + wave*16 + cl;
  const float* P2 = (d ? Pb2 : Pf2) + (size_t)tt*KF;
  #pragma unroll
  for (int r = 0; r < 4; ++r) {
    int node = rq + r;
    if (node < KN) {
      float ht = tanhf(P2[node*F + colg] + acc[r]);
      float heff = reset ? 0.f : H[node*F + colg];
      float z = Zb[node*F + colg];
      float hn = z*heff + (1.f - z)*ht;
      Hst[(size_t)tt*KF + node*F + colg] = hn;
    }
  }
}

// ---------------- upsample + sigmoid: (T,K,32,32)->(T,1,K,64,64) ----------------
__global__ void upsample_kernel(const float* __restrict__ Hf, const float* __restrict__ Hb,
                                float* __restrict__ out) {
  __shared__ float h[HF*HF];
  int b = blockIdx.x; // t*KN + k
  int tid = threadIdx.x;
  #pragma unroll
  for (int i = 0; i < 4; ++i) {
    int idx = tid + i*256;
    h[idx] = Hf[(size_t)b*F + idx] + Hb[(size_t)b*F + idx];
  }
  __syncthreads();
  const float r = 31.0f/63.0f;
  float* op = out + (size_t)b*HM*HM;
  #pragma unroll
  for (int i = 0; i < 16; ++i) {
    int idx = tid + i*256;
    int o = idx >> 6, p = idx & 63;
    float co = (float)o * r; int io = (int)floorf(co); int io1 = min(io+1, HF-1); float wo = co - (float)io;
    float cp = (float)p * r; int jp = (int)floorf(cp); int jp1 = min(jp+1, HF-1); float wp = cp - (float)jp;
    float v = (1.f-wo)*((1.f-wp)*h[io*HF+jp]  + wp*h[io*HF+jp1])
            +      wo *((1.f-wp)*h[io1*HF+jp] + wp*h[io1*HF+jp1]);
    op[idx] = 1.f / (1.f + expf(-v));
  }
}

extern "C" void kernel_launch(void* const* d_in, const int* in_sizes, int n_in,
                              void* d_out, int out_size, void* d_ws, size_t ws_size,
                              hipStream_t stream) {
  const float* x      = (const float*)d_in[0];
  const float* A      = (const float*)d_in[1];
  const float* gcn_W  = (const float*)d_in[2];
  const float* gcn_b  = (const float*)d_in[3];
  const float* tf_gW  = (const float*)d_in[4];
  const float* tf_gb  = (const float*)d_in[5];
  const float* tf_lW  = (const float*)d_in[6];
  const float* tf_lb  = (const float*)d_in[7];
  const float* tb_gW  = (const float*)d_in[8];
  const float* tb_gb  = (const float*)d_in[9];
  const float* tb_lW  = (const float*)d_in[10];
  const float* tb_lb  = (const float*)d_in[11];
  const int*   vid    = (const int*)d_in[12];
  float* out = (float*)d_out;

  float* ws = (float*)d_ws;
  float* An = ws;                  // 196 floats
  int* rf = (int*)(ws + 256);      // 128 ints
  int* rb = (int*)(ws + 512);      // 128 ints
  const size_t SEG = (size_t)TK * F;  // 1,835,008
  float* p = ws + 1024;
  float* Pf[3]; float* Pb[3];
  for (int c = 0; c < 3; ++c) { Pf[c] = p; p += SEG; }
  for (int c = 0; c < 3; ++c) { Pb[c] = p; p += SEG; }
  float* Hstf = p; p += SEG;
  float* Hstb = p; p += SEG;
  float* Zbuf = p; p += 2*KF;
  float* Rbuf = p; p += 2*KF;
  // bf16 region
  __hip_bfloat16* bp = (__hip_bfloat16*)p;
  __hip_bfloat16* feat_bf = bp; bp += SEG;
  __hip_bfloat16* tmpA_bf = bp; bp += SEG;
  __hip_bfloat16* tmpB_bf = bp; bp += SEG;
  const size_t WSEG = (size_t)F*F;
  __hip_bfloat16* wT_gcn[2];
  __hip_bfloat16* wT_g[2][3];
  __hip_bfloat16* wT_l[2][3];
  for (int l = 0; l < 2; ++l) { wT_gcn[l] = bp; bp += WSEG; }
  for (int d = 0; d < 2; ++d)
    for (int c = 0; c < 3; ++c) { wT_g[d][c] = bp; bp += WSEG; }
  for (int d = 0; d < 2; ++d)
    for (int c = 0; c < 3; ++c) { wT_l[d][c] = bp; bp += WSEG; }
  __hip_bfloat16* wScan = bp; bp += 6*WSEG; // [d][g] bottom-half lW transposed

  prep_kernel<<<1, 256, 0, stream>>>(A, vid, An, rf, rb);
  downsample_kernel<<<TK, 256, 0, stream>>>(x, feat_bf);

  // weight convert+transpose (src blocks are contiguous FxF fp32)
  dim3 tgrid(32, 32);
  for (int l = 0; l < 2; ++l)
    convt_kernel<<<tgrid, 256, 0, stream>>>(gcn_W + (size_t)l*WSEG, wT_gcn[l]);
  for (int c = 0; c < 3; ++c) {
    convt_kernel<<<tgrid, 256, 0, stream>>>(tf_gW + (size_t)c*WSEG, wT_g[0][c]);
    convt_kernel<<<tgrid, 256, 0, stream>>>(tb_gW + (size_t)c*WSEG, wT_g[1][c]);
    convt_kernel<<<tgrid, 256, 0, stream>>>(tf_lW + (size_t)c*2*WSEG, wT_l[0][c]);          // top F rows
    convt_kernel<<<tgrid, 256, 0, stream>>>(tb_lW + (size_t)c*2*WSEG, wT_l[1][c]);
    convt_kernel<<<tgrid, 256, 0, stream>>>(tf_lW + (size_t)c*2*WSEG + WSEG, wScan + (size_t)(0*3 + c)*WSEG); // bottom F rows
    convt_kernel<<<tgrid, 256, 0, stream>>>(tb_lW + (size_t)c*2*WSEG + WSEG, wScan + (size_t)(1*3 + c)*WSEG);
  }

  dim3 ggrid(F/128, TK/128); // (8, 14)
  // GCN layers
  for (int l = 0; l < 2; ++l) {
    gemm_mfma<1><<<ggrid, 256, 0, stream>>>(feat_bf, wT_gcn[l], nullptr, tmpA_bf, F);
    anmix_kernel<<<T, 256, 0, stream>>>(tmpA_bf, An, gcn_b + (size_t)l*F, feat_bf, 1);
  }
  // Per-direction input-side precompute: conv_c then P_c for all t
  for (int d = 0; d < 2; ++d) {
    const float* gb = d ? tb_gb : tf_gb;
    const float* lb = d ? tb_lb : tf_lb;
    float** Pd = d ? Pb : Pf;
    for (int c = 0; c < 3; ++c) {
      gemm_mfma<1><<<ggrid, 256, 0, stream>>>(feat_bf, wT_g[d][c], nullptr, tmpA_bf, F);
      anmix_kernel<<<T, 256, 0, stream>>>(tmpA_bf, An, gb + (size_t)c*F, tmpB_bf, 0);
      gemm_mfma<0><<<ggrid, 256, 0, stream>>>(tmpB_bf, wT_l[d][c], lb + (size_t)c*F, Pd[c], F);
    }
  }
  // Sequential GRU scan (fwd + bwd fused per launch), MFMA-based
  for (int t = 0; t < T; ++t) {
    scanA_kernel<<<32, 256, 0, stream>>>(Hstf, Hstb, (const short*)wScan,
                                         Pf[0], Pf[1], Pb[0], Pb[1], rf, rb, Zbuf, Rbuf, t);
    scanB_kernel<<<32, 256, 0, stream>>>(Hstf, Hstb, (const short*)wScan,
                                         Pf[2], Pb[2], rf, rb, Zbuf, Rbuf, t);
  }
  upsample_kernel<<<TK, 256, 0, stream>>>(Hstf, Hstb, out);
}